// Round 15
// baseline (125.337 us; speedup 1.0000x reference)
//
#include <hip/hip_runtime.h>

#define GAMMA 0.1f
#define MIN_R 0.1f

#define NR 256                  // nodes per bin
#define LOG_NR 8
#define RMAXB 512               // max bins (n_nodes <= 131072)
#define SC_BS 4096              // edges per scatter block (private chunk)
#define THR_S 512               // scatter threads (== RMAXB)
#define THR_B 512               // binprocess threads (== 2*NR)
#define CAP 9216                // per-bin LDS sort capacity (edges)

typedef unsigned int u32;

// ---------------- 64-lane inclusive scan via shfl ----------------------------
__device__ __forceinline__ u32 wave_incl_scan(u32 x) {
    #pragma unroll
    for (int d = 1; d < 64; d <<= 1) {
        u32 y = __shfl_up(x, d);
        if ((int)(threadIdx.x & 63) >= d) x += y;
    }
    return x;
}

// ---------------- LJ force accumulate ----------------------------------------
__device__ __forceinline__ void lj_accum(float4 xd, float4 xs,
                                         float& ax, float& ay, float& az)
{
    float dx = xd.x - xs.x, dy = xd.y - xs.y, dz = xd.z - xs.z;
    float r2 = dx * dx + dy * dy + dz * dz;
    float rr = sqrtf(r2);
    float inv_norm = 1.0f / fmaxf(rr, 1e-12f);
    float rc = fmaxf(rr, MIN_R);
    float s1 = 1.0f / rc;                 // RC = 1
    float s2 = s1 * s1;
    float s6 = s2 * s2 * s2;
    float F = 4.0f * s6 * (12.0f * s6 - 6.0f) * s1;
    float sc = F * inv_norm;
    ax += sc * dx; ay += sc * dy; az += sc * dz;
}

// ---------------- k1: block-private bin-sorted scatter (+ xp pack) -----------
// Block b register-stages its SC_BS-edge chunk, bin-sorts it in LDS, writes it
// to pk1[b*SC_BS..] (coalesced), records tab[r][b] = (boff<<13)|cnt.
__global__ __launch_bounds__(THR_S, 4) void scatter_kernel(
    const float* __restrict__ x, const int* __restrict__ src,
    const int* __restrict__ dst, float4* __restrict__ xp,
    u32* __restrict__ pk1, u32* __restrict__ tab,
    int n_nodes, int n_edges, int NBv, int R)
{
    __shared__ u32 payload[SC_BS];        // 16 KB
    __shared__ u32 hist[RMAXB], loff[RMAXB], lcur[RMAXB];
    __shared__ u32 wsb[8];
    const int b = blockIdx.x, t = threadIdx.x;

    // folded prep: pack x -> xp (grid-stride)
    for (int i = b * THR_S + t; i < n_nodes; i += NBv * THR_S)
        xp[i] = make_float4(x[3 * i + 0], x[3 * i + 1], x[3 * i + 2], 0.0f);

    const int s0 = b * SC_BS;
    const int n  = min(SC_BS, n_edges - s0);
    const int lim = s0 + n;

    // register-stage 8 edges (two guarded int4 groups; all indices static)
    u32 da[8], sa[8];
    bool va[8];
    {
        const int eA = s0 + t * 4;
        const int eB = eA + THR_S * 4;
        if (eA + 3 < lim) {
            int4 d4 = *(const int4*)(dst + eA);
            int4 s4 = *(const int4*)(src + eA);
            da[0] = (u32)d4.x; da[1] = (u32)d4.y; da[2] = (u32)d4.z; da[3] = (u32)d4.w;
            sa[0] = (u32)s4.x; sa[1] = (u32)s4.y; sa[2] = (u32)s4.z; sa[3] = (u32)s4.w;
            va[0] = va[1] = va[2] = va[3] = true;
        } else {
            #pragma unroll
            for (int q = 0; q < 4; ++q) {
                int qe = eA + q;
                va[q] = qe < lim;
                da[q] = va[q] ? (u32)dst[qe] : 0u;
                sa[q] = va[q] ? (u32)src[qe] : 0u;
            }
        }
        if (eB + 3 < lim) {
            int4 d4 = *(const int4*)(dst + eB);
            int4 s4 = *(const int4*)(src + eB);
            da[4] = (u32)d4.x; da[5] = (u32)d4.y; da[6] = (u32)d4.z; da[7] = (u32)d4.w;
            sa[4] = (u32)s4.x; sa[5] = (u32)s4.y; sa[6] = (u32)s4.z; sa[7] = (u32)s4.w;
            va[4] = va[5] = va[6] = va[7] = true;
        } else {
            #pragma unroll
            for (int q = 0; q < 4; ++q) {
                int qe = eB + q;
                va[4 + q] = qe < lim;
                da[4 + q] = va[4 + q] ? (u32)dst[qe] : 0u;
                sa[4 + q] = va[4 + q] ? (u32)src[qe] : 0u;
            }
        }
    }

    hist[t] = 0u;                          // THR_S == RMAXB
    __syncthreads();

    // pass 1: chunk histogram from registers
    #pragma unroll
    for (int q = 0; q < 8; ++q)
        if (va[q]) atomicAdd(&hist[da[q] >> LOG_NR], 1u);
    __syncthreads();

    // exclusive scan over 512 bin slots (shfl + wave sums)
    {
        u32 h = hist[t];
        u32 inc = wave_incl_scan(h);
        if ((t & 63) == 63) wsb[t >> 6] = inc;
        __syncthreads();
        u32 pre = 0;
        #pragma unroll
        for (int w = 0; w < 8; ++w) if (w < (t >> 6)) pre += wsb[w];
        u32 ex = pre + inc - h;
        loff[t] = ex; lcur[t] = ex;
    }
    __syncthreads();

    // pass 2: deposit bin-sorted into LDS from registers
    #pragma unroll
    for (int q = 0; q < 8; ++q) {
        if (va[q]) {
            u32 r = da[q] >> LOG_NR;
            u32 w = ((da[q] & (NR - 1)) << 17) | sa[q];
            u32 slot = atomicAdd(&lcur[r], 1u);
            payload[slot] = w;
        }
    }
    __syncthreads();

    // flush chunk (coalesced, block-private) + transposed table column
    for (int j = t; j < n; j += THR_S) pk1[s0 + j] = payload[j];
    if (t < R) tab[(size_t)t * NBv + b] = (loff[t] << 13) | hist[t];
}

// ---------------- k2: fused bin sort-to-node + register process --------------
// Block r: histogram bin r's ragged pk1 segments (global), LDS counting-sort
// them into 'sorted', then 2-threads-per-node register accumulation -> out.
__global__ __launch_bounds__(THR_B, 4) void binprocess_kernel(
    const float4* __restrict__ xp, const u32* __restrict__ pk1,
    const u32* __restrict__ tab, const float* __restrict__ v,
    float* __restrict__ out, int n_nodes, int NBv, int R)
{
    __shared__ u32 sorted[CAP];           // 36 KB
    __shared__ u32 hist[NR], cur[NR], ns[NR];
    __shared__ u32 wred[8];
    const int r = blockIdx.x, t = threadIdx.x;
    const u32* __restrict__ trow = tab + (size_t)r * NBv;

    // ---- phase 0: total edge count (reduction) + hist zero -----------------
    u32 csum = 0;
    for (int j = t; j < NBv; j += THR_B) csum += trow[j] & 8191u;
    #pragma unroll
    for (int d = 32; d > 0; d >>= 1) csum += __shfl_down(csum, d);
    if ((t & 63) == 0) wred[t >> 6] = csum;
    if (t < NR) hist[t] = 0u;
    __syncthreads();
    u32 total = 0;
    #pragma unroll
    for (int w = 0; w < 8; ++w) total += wred[w];
    __syncthreads();

    // ---- phase 1: node histogram from global segments ----------------------
    for (int j = t; j < NBv; j += THR_B) {
        u32 w = trow[j];
        int cnt = (int)(w & 8191u);
        const u32* seg = pk1 + (size_t)j * SC_BS + (w >> 13);
        int k = 0;
        for (; k + 3 < cnt; k += 4) {
            u32 w0 = seg[k], w1 = seg[k + 1], w2 = seg[k + 2], w3 = seg[k + 3];
            atomicAdd(&hist[w0 >> 17], 1u);
            atomicAdd(&hist[w1 >> 17], 1u);
            atomicAdd(&hist[w2 >> 17], 1u);
            atomicAdd(&hist[w3 >> 17], 1u);
        }
        for (; k < cnt; ++k) atomicAdd(&hist[seg[k] >> 17], 1u);
    }
    __syncthreads();

    // ---- phase 2: exclusive scan over 256 node counters --------------------
    {
        u32 h = (t < NR) ? hist[t] : 0u;
        u32 inc = wave_incl_scan(h);
        if ((t & 63) == 63 && t < NR) wred[t >> 6] = inc;
        __syncthreads();
        u32 pre = 0;
        #pragma unroll
        for (int w = 0; w < 4; ++w) if (w < (t >> 6)) pre += wred[w];
        if (t < NR) {
            u32 ex = pre + inc - h;
            ns[t] = ex; cur[t] = ex;
        }
    }
    __syncthreads();

    if (total <= CAP) {
        // ---- phase 3: counting-sort from global into 'sorted' --------------
        for (int j = t; j < NBv; j += THR_B) {
            u32 w = trow[j];
            int cnt = (int)(w & 8191u);
            const u32* seg = pk1 + (size_t)j * SC_BS + (w >> 13);
            int k = 0;
            for (; k + 3 < cnt; k += 4) {
                u32 w0 = seg[k], w1 = seg[k + 1], w2 = seg[k + 2], w3 = seg[k + 3];
                u32 p0 = atomicAdd(&cur[w0 >> 17], 1u);
                u32 p1 = atomicAdd(&cur[w1 >> 17], 1u);
                u32 p2 = atomicAdd(&cur[w2 >> 17], 1u);
                u32 p3 = atomicAdd(&cur[w3 >> 17], 1u);
                sorted[p0] = w0 & 0x1FFFFu;
                sorted[p1] = w1 & 0x1FFFFu;
                sorted[p2] = w2 & 0x1FFFFu;
                sorted[p3] = w3 & 0x1FFFFu;
            }
            for (; k < cnt; ++k) {
                u32 w0 = seg[k];
                u32 p0 = atomicAdd(&cur[w0 >> 17], 1u);
                sorted[p0] = w0 & 0x1FFFFu;
            }
        }
        __syncthreads();

        // ---- phase 4: per-node register gather (2 thr/node) + fused out ----
        const int dl = t >> 1, half = t & 1;
        const int node = (r << LOG_NR) + dl;
        if (node < n_nodes) {
            const float4 xd = xp[node];
            const int ee0 = (int)ns[dl];
            const int ee1 = (dl < NR - 1) ? (int)ns[dl + 1] : (int)total;
            float ax = 0.f, ay = 0.f, az = 0.f;
            int e = ee0 + half;
            for (; e + 6 < ee1; e += 8) {
                u32 q0 = sorted[e], q1 = sorted[e + 2];
                u32 q2 = sorted[e + 4], q3 = sorted[e + 6];
                float4 a0 = xp[q0], a1 = xp[q1], a2 = xp[q2], a3 = xp[q3];
                lj_accum(xd, a0, ax, ay, az);
                lj_accum(xd, a1, ax, ay, az);
                lj_accum(xd, a2, ax, ay, az);
                lj_accum(xd, a3, ax, ay, az);
            }
            for (; e < ee1; e += 2) {
                float4 a = xp[sorted[e]];
                lj_accum(xd, a, ax, ay, az);
            }
            ax += __shfl_xor(ax, 1);
            ay += __shfl_xor(ay, 1);
            az += __shfl_xor(az, 1);
            if (half == 0) {
                out[3 * node + 0] = ax - GAMMA * v[3 * node + 0];
                out[3 * node + 1] = ay - GAMMA * v[3 * node + 1];
                out[3 * node + 2] = az - GAMMA * v[3 * node + 2];
            }
        }
    } else {
        // ---- slow correctness path (bin overflow): LDS-atomic accumulate ---
        float* acc = (float*)sorted;       // 256*3 floats = 3 KB
        for (int i = t; i < NR * 3; i += THR_B) acc[i] = 0.f;
        __syncthreads();
        for (int j = t; j < NBv; j += THR_B) {
            u32 w = trow[j];
            int cnt = (int)(w & 8191u);
            const u32* seg = pk1 + (size_t)j * SC_BS + (w >> 13);
            for (int k = 0; k < cnt; ++k) {
                u32 w0 = seg[k];
                int u = (int)(w0 >> 17);
                int node = (r << LOG_NR) + u;
                float4 xs = xp[w0 & 0x1FFFFu];
                float4 xd = xp[node];
                float ax = 0.f, ay = 0.f, az = 0.f;
                lj_accum(xd, xs, ax, ay, az);
                unsafeAtomicAdd(&acc[3 * u + 0], ax);
                unsafeAtomicAdd(&acc[3 * u + 1], ay);
                unsafeAtomicAdd(&acc[3 * u + 2], az);
            }
        }
        __syncthreads();
        for (int i = t; i < NR; i += THR_B) {
            int node = (r << LOG_NR) + i;
            if (node < n_nodes) {
                out[3 * node + 0] = acc[3 * i + 0] - GAMMA * v[3 * node + 0];
                out[3 * node + 1] = acc[3 * i + 1] - GAMMA * v[3 * node + 1];
                out[3 * node + 2] = acc[3 * i + 2] - GAMMA * v[3 * node + 2];
            }
        }
    }
}

// ---------------- fallback path ----------------------------------------------
__global__ void init_out_kernel(const float* __restrict__ v,
                                float* __restrict__ out, int n) {
    int i = blockIdx.x * blockDim.x + threadIdx.x;
    if (i < n) out[i] = -GAMMA * v[i];
}

__global__ void edge_atomic_kernel(const float* __restrict__ x,
                                   const int* __restrict__ src,
                                   const int* __restrict__ dst,
                                   float* __restrict__ out, int n_edges) {
    int e = blockIdx.x * blockDim.x + threadIdx.x;
    if (e < n_edges) {
        const int s3 = 3 * src[e], d3 = 3 * dst[e];
        float dx = x[d3 + 0] - x[s3 + 0];
        float dy = x[d3 + 1] - x[s3 + 1];
        float dz = x[d3 + 2] - x[s3 + 2];
        float r2 = dx * dx + dy * dy + dz * dz;
        float rr = sqrtf(r2);
        float inv_norm = 1.0f / fmaxf(rr, 1e-12f);
        float rc = fmaxf(rr, MIN_R);
        float s1 = 1.0f / rc;
        float s2 = s1 * s1;
        float s6 = s2 * s2 * s2;
        float F = 4.0f * s6 * (12.0f * s6 - 6.0f) * s1;
        float sc = F * inv_norm;
        unsafeAtomicAdd(&out[d3 + 0], sc * dx);
        unsafeAtomicAdd(&out[d3 + 1], sc * dy);
        unsafeAtomicAdd(&out[d3 + 2], sc * dz);
    }
}

extern "C" void kernel_launch(void* const* d_in, const int* in_sizes, int n_in,
                              void* d_out, int out_size, void* d_ws, size_t ws_size,
                              hipStream_t stream) {
    const float* x   = (const float*)d_in[0];
    const float* v   = (const float*)d_in[1];
    const int*   src = (const int*)d_in[2];
    const int*   dst = (const int*)d_in[3];
    float* out = (float*)d_out;

    const int n_out   = out_size;
    const int n_nodes = out_size / 3;
    const int n_edges = in_sizes[2];
    const int R   = (n_nodes + NR - 1) / NR;
    const int NBv = (n_edges + SC_BS - 1) / SC_BS;

    // ---- ws layout (bytes) ----
    size_t off = 0;
    auto take = [&off](size_t bytes) {
        size_t o = off;
        off = (off + bytes + 63) & ~(size_t)63;
        return o;
    };
    const size_t xp_o  = take((size_t)n_nodes * 16);
    const size_t tab_o = take((size_t)R * NBv * 4);
    const size_t pk1_o = take((size_t)NBv * SC_BS * 4);
    const size_t need = off;

    const int blk = 256;
    if (n_nodes <= (1 << 17) && R <= RMAXB && need <= ws_size) {
        float4* xp = (float4*)((char*)d_ws + xp_o);
        u32* tab   = (u32*)((char*)d_ws + tab_o);
        u32* pk1   = (u32*)((char*)d_ws + pk1_o);

        scatter_kernel<<<NBv, THR_S, 0, stream>>>(x, src, dst, xp, pk1, tab,
                                                  n_nodes, n_edges, NBv, R);
        binprocess_kernel<<<R, THR_B, 0, stream>>>(xp, pk1, tab, v, out,
                                                   n_nodes, NBv, R);
    } else {
        init_out_kernel<<<(n_out + blk - 1) / blk, blk, 0, stream>>>(v, out, n_out);
        edge_atomic_kernel<<<(n_edges + blk - 1) / blk, blk, 0, stream>>>(
            x, src, dst, out, n_edges);
    }
}

// Round 16
// 111.811 us; speedup vs baseline: 1.1210x; 1.1210x over previous
//
#include <hip/hip_runtime.h>

#define GAMMA 0.1f
#define MIN_R 0.1f

#define NR 256                  // nodes per bin
#define LOG_NR 8
#define RMAXB 512               // max bins (n_nodes <= 131072)
#define SC_BS 8192              // edges per scatter block (private chunk)
#define THR_S 512               // scatter threads (== RMAXB)
#define THR_B 512               // binprocess threads (== 2*NR)
#define CAP 9216                // per-bin LDS sort capacity (edges)
#define NBMAX 512               // max scatter chunks (n_edges <= 4.19M)

typedef unsigned int u32;
typedef unsigned short u16;

// ---------------- 64-lane inclusive scan via shfl ----------------------------
__device__ __forceinline__ u32 wave_incl_scan(u32 x) {
    #pragma unroll
    for (int d = 1; d < 64; d <<= 1) {
        u32 y = __shfl_up(x, d);
        if ((int)(threadIdx.x & 63) >= d) x += y;
    }
    return x;
}

// ---------------- LJ force accumulate ----------------------------------------
__device__ __forceinline__ void lj_accum(float4 xd, float4 xs,
                                         float& ax, float& ay, float& az)
{
    float dx = xd.x - xs.x, dy = xd.y - xs.y, dz = xd.z - xs.z;
    float r2 = dx * dx + dy * dy + dz * dz;
    float rr = sqrtf(r2);
    float inv_norm = 1.0f / fmaxf(rr, 1e-12f);
    float rc = fmaxf(rr, MIN_R);
    float s1 = 1.0f / rc;                 // RC = 1
    float s2 = s1 * s1;
    float s6 = s2 * s2 * s2;
    float F = 4.0f * s6 * (12.0f * s6 - 6.0f) * s1;
    float sc = F * inv_norm;
    ax += sc * dx; ay += sc * dy; az += sc * dz;
}

// ---------------- k1: block-private bin-sorted scatter (+ xp pack) -----------
// Block b sorts its SC_BS-edge chunk by bin in LDS, writes it to pk1[b*SC_BS..]
// (coalesced), records tab[b][r] = (loff<<16)|cnt  (coalesced write).
__global__ __launch_bounds__(THR_S) void scatter_kernel(
    const float* __restrict__ x, const int* __restrict__ src,
    const int* __restrict__ dst, float4* __restrict__ xp,
    u32* __restrict__ pk1, u32* __restrict__ tab,
    int n_nodes, int n_edges, int NBv, int R)
{
    __shared__ u32 payload[SC_BS];        // 32 KB
    __shared__ u32 hist[RMAXB], loff[RMAXB], lcur[RMAXB];   // 6 KB
    __shared__ u32 wsb[8];
    const int b = blockIdx.x, t = threadIdx.x;

    // folded prep: pack x -> xp (grid-stride)
    for (int i = b * THR_S + t; i < n_nodes; i += NBv * THR_S)
        xp[i] = make_float4(x[3 * i + 0], x[3 * i + 1], x[3 * i + 2], 0.0f);

    const int s0 = b * SC_BS;
    const int n  = min(SC_BS, n_edges - s0);
    const int lim = s0 + n;

    hist[t] = 0u;                          // THR_S == RMAXB
    __syncthreads();

    // pass 1: chunk histogram over bins
    for (int e = s0 + t * 4; e < lim; e += THR_S * 4) {
        if (e + 3 < lim) {
            int4 d4 = *(const int4*)(dst + e);
            atomicAdd(&hist[(u32)d4.x >> LOG_NR], 1u);
            atomicAdd(&hist[(u32)d4.y >> LOG_NR], 1u);
            atomicAdd(&hist[(u32)d4.z >> LOG_NR], 1u);
            atomicAdd(&hist[(u32)d4.w >> LOG_NR], 1u);
        } else {
            for (int q = e; q < lim; ++q)
                atomicAdd(&hist[(u32)dst[q] >> LOG_NR], 1u);
        }
    }
    __syncthreads();

    // exclusive scan over 512 bin slots (shfl + wave sums)
    {
        u32 h = hist[t];
        u32 inc = wave_incl_scan(h);
        if ((t & 63) == 63) wsb[t >> 6] = inc;
        __syncthreads();
        u32 pre = 0;
        #pragma unroll
        for (int w = 0; w < 8; ++w) if (w < (t >> 6)) pre += wsb[w];
        u32 ex = pre + inc - h;
        loff[t] = ex; lcur[t] = ex;
    }
    __syncthreads();

    // pass 2: deposit bin-sorted into LDS
    for (int e = s0 + t * 4; e < lim; e += THR_S * 4) {
        if (e + 3 < lim) {
            int4 d4 = *(const int4*)(dst + e);
            int4 s4 = *(const int4*)(src + e);
            #pragma unroll
            for (int q = 0; q < 4; ++q) {
                u32 d = (u32)((q == 0) ? d4.x : (q == 1) ? d4.y : (q == 2) ? d4.z : d4.w);
                u32 sv = (u32)((q == 0) ? s4.x : (q == 1) ? s4.y : (q == 2) ? s4.z : s4.w);
                u32 r = d >> LOG_NR;
                u32 w = ((d & (NR - 1)) << 17) | sv;
                u32 slot = atomicAdd(&lcur[r], 1u);
                payload[slot] = w;
            }
        } else {
            for (int q = e; q < lim; ++q) {
                u32 d = (u32)dst[q];
                u32 sv = (u32)src[q];
                u32 r = d >> LOG_NR;
                u32 w = ((d & (NR - 1)) << 17) | sv;
                u32 slot = atomicAdd(&lcur[r], 1u);
                payload[slot] = w;
            }
        }
    }
    __syncthreads();

    // flush chunk (coalesced, block-private) + coalesced table row
    for (int j = t; j < n; j += THR_S) pk1[s0 + j] = payload[j];
    if (t < R) tab[(size_t)b * R + t] = (loff[t] << 16) | hist[t];
}

// ---------------- k2: fused bin sort-to-node + register process --------------
// Block r: cache tab row in LDS, stage bin r's segments into LDS (+hist),
// LDS counting-sort, then 2-threads-per-node register accumulation -> out.
__global__ __launch_bounds__(THR_B, 4) void binprocess_kernel(
    const float4* __restrict__ xp, const u32* __restrict__ pk1,
    const u32* __restrict__ tab, const float* __restrict__ v,
    float* __restrict__ out, int n_nodes, int NBv, int R)
{
    __shared__ u32 buf[CAP];              // 36 KB
    __shared__ u32 sorted[CAP];           // 36 KB
    __shared__ u32 tabw[NBMAX];           // 2 KB
    __shared__ u16 segoff[NBMAX];         // 1 KB
    __shared__ u32 hist[NR], cur[NR];     // 2 KB
    __shared__ u32 wsb[8];
    __shared__ u32 shv[1];
    const int r = blockIdx.x, t = threadIdx.x;

    // ---- phase 0: cache tab row (strided global, once), scan seg counts ----
    u32 w0 = 0;
    if (t < NBv) w0 = tab[(size_t)t * R + r];
    tabw[t] = w0;                          // THR_B == NBMAX
    u32 cnt0 = w0 & 0xFFFFu;
    u32 inc0 = wave_incl_scan(cnt0);
    if ((t & 63) == 63) wsb[t >> 6] = inc0;
    if (t < NR) hist[t] = 0u;
    __syncthreads();
    u32 pre0 = 0;
    #pragma unroll
    for (int w = 0; w < 8; ++w) if (w < (t >> 6)) pre0 += wsb[w];
    u32 sincl = pre0 + inc0;
    segoff[t] = (u16)(sincl - cnt0);
    if (t == THR_B - 1) shv[0] = sincl;
    __syncthreads();
    const u32 total = shv[0];

    if (total <= CAP) {
        // ---- phase 1: stage segments into LDS + node histogram -------------
        if (t < NBv) {
            u32 w = tabw[t];
            int cnt = (int)(w & 0xFFFFu);
            const u32* seg = pk1 + (size_t)t * SC_BS + (w >> 16);
            u32 base = segoff[t];
            int k = 0;
            for (; k + 3 < cnt; k += 4) {
                u32 a = seg[k], b2 = seg[k + 1], c = seg[k + 2], d = seg[k + 3];
                buf[base + k] = a; buf[base + k + 1] = b2;
                buf[base + k + 2] = c; buf[base + k + 3] = d;
                atomicAdd(&hist[a >> 17], 1u);
                atomicAdd(&hist[b2 >> 17], 1u);
                atomicAdd(&hist[c >> 17], 1u);
                atomicAdd(&hist[d >> 17], 1u);
            }
            for (; k < cnt; ++k) {
                u32 a = seg[k];
                buf[base + k] = a;
                atomicAdd(&hist[a >> 17], 1u);
            }
        }
        __syncthreads();

        // ---- phase 2: exclusive scan over 256 node counters ----------------
        {
            u32 h = (t < NR) ? hist[t] : 0u;
            u32 inc = wave_incl_scan(h);
            if ((t & 63) == 63 && t < NR) wsb[t >> 6] = inc;
            __syncthreads();
            u32 pre = 0;
            #pragma unroll
            for (int w = 0; w < 4; ++w) if (w < (t >> 6)) pre += wsb[w];
            if (t < NR) cur[t] = pre + inc - h;
        }
        __syncthreads();

        // ---- phase 3: LDS counting-sort (keep only src id) -----------------
        for (int i = t; i < (int)total; i += THR_B) {
            u32 w = buf[i];
            u32 p = atomicAdd(&cur[w >> 17], 1u);
            sorted[p] = w & 0x1FFFFu;
        }
        __syncthreads();

        // ---- phase 4: per-node register gather (2 thr/node) + fused out ----
        // after sort, cur[d] == end position of node d; start = cur[d-1] (0 for d=0)
        const int dl = t >> 1, half = t & 1;
        const int node = (r << LOG_NR) + dl;
        if (node < n_nodes) {
            const float4 xd = xp[node];
            const int ee1 = (int)cur[dl];
            const int ee0 = dl ? (int)cur[dl - 1] : 0;
            float ax = 0.f, ay = 0.f, az = 0.f;
            int e = ee0 + half;
            for (; e + 6 < ee1; e += 8) {
                u32 q0 = sorted[e], q1 = sorted[e + 2];
                u32 q2 = sorted[e + 4], q3 = sorted[e + 6];
                float4 a0 = xp[q0], a1 = xp[q1], a2 = xp[q2], a3 = xp[q3];
                lj_accum(xd, a0, ax, ay, az);
                lj_accum(xd, a1, ax, ay, az);
                lj_accum(xd, a2, ax, ay, az);
                lj_accum(xd, a3, ax, ay, az);
            }
            for (; e < ee1; e += 2) {
                float4 a = xp[sorted[e]];
                lj_accum(xd, a, ax, ay, az);
            }
            ax += __shfl_xor(ax, 1);
            ay += __shfl_xor(ay, 1);
            az += __shfl_xor(az, 1);
            if (half == 0) {
                out[3 * node + 0] = ax - GAMMA * v[3 * node + 0];
                out[3 * node + 1] = ay - GAMMA * v[3 * node + 1];
                out[3 * node + 2] = az - GAMMA * v[3 * node + 2];
            }
        }
    } else {
        // ---- slow correctness path (bin overflow): LDS-atomic accumulate ---
        float* acc = (float*)buf;          // 256*3 floats = 3 KB
        for (int i = t; i < NR * 3; i += THR_B) acc[i] = 0.f;
        __syncthreads();
        if (t < NBv) {
            u32 w = tabw[t];
            int cnt = (int)(w & 0xFFFFu);
            const u32* seg = pk1 + (size_t)t * SC_BS + (w >> 16);
            for (int k = 0; k < cnt; ++k) {
                u32 w0 = seg[k];
                int u = (int)(w0 >> 17);
                int node = (r << LOG_NR) + u;
                float4 xs = xp[w0 & 0x1FFFFu];
                float4 xd = xp[node];
                float ax = 0.f, ay = 0.f, az = 0.f;
                lj_accum(xd, xs, ax, ay, az);
                unsafeAtomicAdd(&acc[3 * u + 0], ax);
                unsafeAtomicAdd(&acc[3 * u + 1], ay);
                unsafeAtomicAdd(&acc[3 * u + 2], az);
            }
        }
        __syncthreads();
        for (int i = t; i < NR; i += THR_B) {
            int node = (r << LOG_NR) + i;
            if (node < n_nodes) {
                out[3 * node + 0] = acc[3 * i + 0] - GAMMA * v[3 * node + 0];
                out[3 * node + 1] = acc[3 * i + 1] - GAMMA * v[3 * node + 1];
                out[3 * node + 2] = acc[3 * i + 2] - GAMMA * v[3 * node + 2];
            }
        }
    }
}

// ---------------- fallback path ----------------------------------------------
__global__ void init_out_kernel(const float* __restrict__ v,
                                float* __restrict__ out, int n) {
    int i = blockIdx.x * blockDim.x + threadIdx.x;
    if (i < n) out[i] = -GAMMA * v[i];
}

__global__ void edge_atomic_kernel(const float* __restrict__ x,
                                   const int* __restrict__ src,
                                   const int* __restrict__ dst,
                                   float* __restrict__ out, int n_edges) {
    int e = blockIdx.x * blockDim.x + threadIdx.x;
    if (e < n_edges) {
        const int s3 = 3 * src[e], d3 = 3 * dst[e];
        float dx = x[d3 + 0] - x[s3 + 0];
        float dy = x[d3 + 1] - x[s3 + 1];
        float dz = x[d3 + 2] - x[s3 + 2];
        float r2 = dx * dx + dy * dy + dz * dz;
        float rr = sqrtf(r2);
        float inv_norm = 1.0f / fmaxf(rr, 1e-12f);
        float rc = fmaxf(rr, MIN_R);
        float s1 = 1.0f / rc;
        float s2 = s1 * s1;
        float s6 = s2 * s2 * s2;
        float F = 4.0f * s6 * (12.0f * s6 - 6.0f) * s1;
        float sc = F * inv_norm;
        unsafeAtomicAdd(&out[d3 + 0], sc * dx);
        unsafeAtomicAdd(&out[d3 + 1], sc * dy);
        unsafeAtomicAdd(&out[d3 + 2], sc * dz);
    }
}

extern "C" void kernel_launch(void* const* d_in, const int* in_sizes, int n_in,
                              void* d_out, int out_size, void* d_ws, size_t ws_size,
                              hipStream_t stream) {
    const float* x   = (const float*)d_in[0];
    const float* v   = (const float*)d_in[1];
    const int*   src = (const int*)d_in[2];
    const int*   dst = (const int*)d_in[3];
    float* out = (float*)d_out;

    const int n_out   = out_size;
    const int n_nodes = out_size / 3;
    const int n_edges = in_sizes[2];
    const int R   = (n_nodes + NR - 1) / NR;
    const int NBv = (n_edges + SC_BS - 1) / SC_BS;

    // ---- ws layout (bytes) ----
    size_t off = 0;
    auto take = [&off](size_t bytes) {
        size_t o = off;
        off = (off + bytes + 63) & ~(size_t)63;
        return o;
    };
    const size_t xp_o  = take((size_t)n_nodes * 16);
    const size_t tab_o = take((size_t)NBv * R * 4);
    const size_t pk1_o = take((size_t)NBv * SC_BS * 4);
    const size_t need = off;

    const int blk = 256;
    if (n_nodes <= (1 << 17) && R <= RMAXB && NBv <= NBMAX && need <= ws_size) {
        float4* xp = (float4*)((char*)d_ws + xp_o);
        u32* tab   = (u32*)((char*)d_ws + tab_o);
        u32* pk1   = (u32*)((char*)d_ws + pk1_o);

        scatter_kernel<<<NBv, THR_S, 0, stream>>>(x, src, dst, xp, pk1, tab,
                                                  n_nodes, n_edges, NBv, R);
        binprocess_kernel<<<R, THR_B, 0, stream>>>(xp, pk1, tab, v, out,
                                                   n_nodes, NBv, R);
    } else {
        init_out_kernel<<<(n_out + blk - 1) / blk, blk, 0, stream>>>(v, out, n_out);
        edge_atomic_kernel<<<(n_edges + blk - 1) / blk, blk, 0, stream>>>(
            x, src, dst, out, n_edges);
    }
}